// Round 1
// baseline (111.483 us; speedup 1.0000x reference)
//
#include <hip/hip_runtime.h>

#define BB 4
#define CC 3
#define HH 512
#define WW 512
#define NS 81              // 9 x 9 shifts
#define IMG (HH * WW)
#define CHW (CC * IMG)
#define STRIP 32           // rows per k_sims block (8 rows per wave)
#define NSTRIP (HH / STRIP)              // 16
#define NBLK (BB * CC * NSTRIP * 9)      // 1728 blocks (one sx each)

// Cross-kernel scratch lives in module __device__ globals instead of d_ws:
//  - removes the 2.6 KB memset node (no zero-init needed: every slot is
//    unconditionally overwritten every launch -> no cross-iteration state)
//  - tests whether the harness's 256 MiB workspace poison-fill (~43 us,
//    the top-5 dispatches in the R11 profile) drops out of the timed graph
__device__ double g_part[NBLK][9];   // per-block fp64 partials, 124 KB
__device__ int    g_best[BB];        // argmax index per batch

// constant-index component select (folds after full unroll)
#define C4(v, i) ((i) == 0 ? (v).x : (i) == 1 ? (v).y : (i) == 2 ? (v).z : (v).w)

// sim(b,sx,sy) = sum over c,i,j (both (i,j) and (i+sx,j+sy) in bounds) of
//               x[b,c,i,j] * x_ref[b,c,i+sx,j+sy]
// R12: halo via direct VMEM loads (was 8 ds_bpermute/row on the load->FMA
// critical path); partials to g_part (no fp64 atomics, no zeroed buffer).
__global__ __launch_bounds__(256, 4) void k_sims(const float* __restrict__ xref,
                                                 const float* __restrict__ x) {
    int bid  = blockIdx.x;
    int sxi  = bid % 9;                  // sx = sxi - 4
    int tmp  = bid / 9;
    int strip = tmp % NSTRIP;
    int bc   = tmp / NSTRIP;
    const float* xp = x    + (size_t)bc * IMG;
    const float* rp = xref + (size_t)bc * IMG;
    int tid  = threadIdx.x;
    int lane = tid & 63;
    int wave = tid >> 6;
    int j0   = lane << 3;                // 8 floats per lane
    int sx   = sxi - 4;
    int ip0  = strip * STRIP + wave * 8;

    float acc[9];
#pragma unroll
    for (int s = 0; s < 9; ++s) acc[s] = 0.f;

#pragma unroll
    for (int rr = 0; rr < 8; ++rr) {
        int ip = ip0 + rr;               // x row (always in bounds)
        int ii = ip + sx;                // ref row (wave-uniform test)
        if ((unsigned)ii >= HH) continue;

        const float* xrow = xp + ip * WW + j0;
        const float* rrow = rp + ii * WW + j0;
        float4 xa = *(const float4*)(xrow);        // x   cols j0   .. j0+3
        float4 xb = *(const float4*)(xrow + 4);    // x   cols j0+4 .. j0+7

        // ref window cols j0-4 .. j0+11: four 16B-aligned dwordx4 loads.
        // (lane*8-4)*4 and (lane*8+8)*4 are both 16B-aligned. Lane 0/63
        // redirect in-row (no OOB anywhere) then zero-select the halo.
        const float4* pp = (const float4*)(rrow + (lane == 0  ? 0 : -4));
        const float4* np = (const float4*)(rrow + (lane == 63 ? 0 :  8));
        float4 pv = *pp;                           // ref cols j0-4 .. j0-1
        float4 ra = *(const float4*)(rrow);        // ref cols j0   .. j0+3
        float4 rb = *(const float4*)(rrow + 4);    // ref cols j0+4 .. j0+7
        float4 nv = *np;                           // ref cols j0+8 .. j0+11
        if (lane == 0)  pv = make_float4(0.f, 0.f, 0.f, 0.f);  // cols < 0
        if (lane == 63) nv = make_float4(0.f, 0.f, 0.f, 0.f);  // cols >= 512

#pragma unroll
        for (int syi = 0; syi < 9; ++syi) {
#pragma unroll
            for (int k = 0; k < 8; ++k) {
                int i = k + syi;         // window index 0..15 (constant)
                float wv = (i < 4)  ? C4(pv, i)
                         : (i < 8)  ? C4(ra, i - 4)
                         : (i < 12) ? C4(rb, i - 8)
                         :            C4(nv, i - 12);
                float xv = (k < 4) ? C4(xa, k) : C4(xb, k - 4);
                acc[syi] += xv * wv;
            }
        }
    }

    // wave reduce (fp32), block combine in fp64, store per-block partial.
    // Numerics: identical per-thread/wave sums to R11; only the final
    // 48-partial combine order changes (fixed vs atomic-nondeterministic,
    // jitter ~1e-10 vs inter-sim gaps O(100) -> argmax stable).
    __shared__ float part[4][9];
#pragma unroll
    for (int s = 0; s < 9; ++s) {
        float v = acc[s];
        for (int off = 32; off; off >>= 1) v += __shfl_down(v, off, 64);
        if (lane == 0) part[wave][s] = v;
    }
    __syncthreads();
    if (tid < 9) {
        g_part[bid][tid] = (double)part[0][tid] + (double)part[1][tid]
                         + (double)part[2][tid] + (double)part[3][tid];
    }
}

// Tiny reduce: one block per batch sums 48 fp64 partials per (sx,sy),
// first-index argmax (matches jnp.argmax), writes g_best + shift tail.
__global__ __launch_bounds__(128) void k_reduce(float* __restrict__ outTail) {
    int b = blockIdx.x;
    int t = threadIdx.x;
    __shared__ double vals[NS];
    if (t < NS) {
        int sxi = t / 9;
        int syi = t % 9;
        double s = 0.0;
#pragma unroll
        for (int c = 0; c < CC; ++c)
#pragma unroll
            for (int st = 0; st < NSTRIP; ++st) {
                int bid = ((b * CC + c) * NSTRIP + st) * 9 + sxi;
                s += g_part[bid][syi];
            }
        vals[t] = s;
    }
    __syncthreads();
    if (t == 0) {
        int best = 0;
        double bv = vals[0];
        for (int i = 1; i < NS; ++i)
            if (vals[i] > bv) { bv = vals[i]; best = i; }   // strict >: first index wins
        g_best[b] = best;
        outTail[b * 2]     = (float)(best / 9 - 4);
        outTail[b * 2 + 1] = (float)(best % 9 - 4);
    }
}

// Pure shift-copy: argmax preamble gone (reads precomputed g_best[b],
// wave-uniform scalar load). Copy body unchanged from R11 (proven exact).
__global__ __launch_bounds__(256) void k_apply(const float* __restrict__ x,
                                               float* __restrict__ out) {
    int blk = blockIdx.x;
    int bc  = blk >> 8;                 // 256 blocks per image (512 rows / 2)
    int tid = threadIdx.x;
    int b   = bc / CC;

    int bi = g_best[b];
    int sx = bi / 9 - 4;
    int sy = bi % 9 - 4;

    int row = ((blk & 255) << 1) + (tid >> 7);
    int j0  = (tid & 127) << 2;
    int is  = row - sx;
    float4 v = make_float4(0.f, 0.f, 0.f, 0.f);
    if ((unsigned)is < HH) {
        const float* src = x + (size_t)bc * IMG + is * WW;
        int js0 = j0 - sy;
        if (js0 >= 0 && js0 + 3 < WW) {
            v = *(const float4*)(src + js0);   // 4B-aligned dwordx4, exact (R2-R12)
        } else {
            float* vv = (float*)&v;
#pragma unroll
            for (int k = 0; k < 4; ++k) {
                int js = js0 + k;
                if ((unsigned)js < WW) vv[k] = src[js];
            }
        }
    }
    *(float4*)(out + (size_t)bc * IMG + row * WW + j0) = v;
}

extern "C" void kernel_launch(void* const* d_in, const int* in_sizes, int n_in,
                              void* d_out, int out_size, void* d_ws, size_t ws_size,
                              hipStream_t stream) {
    const float* xref = (const float*)d_in[0];
    const float* x    = (const float*)d_in[1];
    float* out = (float*)d_out;
    (void)d_ws; (void)ws_size;          // workspace intentionally unused

    k_sims<<<NBLK, 256, 0, stream>>>(xref, x);
    k_reduce<<<BB, 128, 0, stream>>>(out + (size_t)BB * CHW);

    int applyBlocks = (BB * CC * HH) / 2;   // 3072
    k_apply<<<applyBlocks, 256, 0, stream>>>(x, out);
}

// Round 2
// 95.803 us; speedup vs baseline: 1.1637x; 1.1637x over previous
//
#include <hip/hip_runtime.h>

#define BB 4
#define CC 3
#define HH 512
#define WW 512
#define NS 81              // 9 x 9 shifts
#define IMG (HH * WW)
#define CHW (CC * IMG)
#define STRIP 16           // rows per k_sims block
#define NSTRIPS (HH / STRIP)             // 32
#define NBLK (BB * CC * NSTRIPS)         // 384 blocks (ALL sx per block)
#define SLOTS (CC * NSTRIPS)             // 96 partials per (b, sim)

// R13: restructure k_sims so all 9 sx live in ONE block (one sx per wave).
// Old structure gave the same (bc,strip) to 9 different blocks scattered
// across CUs/XCDs -> every strip re-read ~9x from L2/LLC (~the 35-40 us
// plateau that survived 7 single-structure levers). Now the 9 waves share
// one CU's L1 for the 9x row reuse; per-wave inner body is R11's proven code.
__device__ double g_part[(size_t)BB * NS * SLOTS];   // 249 KB, fully rewritten each launch
__device__ int    g_best[BB];

// constant-index component select (folds after full unroll)
#define C4(v, i) ((i) == 0 ? (v).x : (i) == 1 ? (v).y : (i) == 2 ? (v).z : (v).w)

// sim(b,sx,sy) = sum over c,i,j (both (i,j) and (i+sx,j+sy) in bounds) of
//               x[b,c,i,j] * x_ref[b,c,i+sx,j+sy]
__global__ __launch_bounds__(576) void k_sims(const float* __restrict__ xref,
                                              const float* __restrict__ x) {
    int bid   = blockIdx.x;
    int strip = bid % NSTRIPS;
    int bc    = bid / NSTRIPS;
    int b     = bc / CC;
    const float* xp = x    + (size_t)bc * IMG;
    const float* rp = xref + (size_t)bc * IMG;
    int tid  = threadIdx.x;
    int lane = tid & 63;
    int sxi  = tid >> 6;                 // wave index == sx index (9 waves)
    int j0   = lane << 3;                // 8 floats per lane
    int sx   = sxi - 4;
    int ip0  = strip * STRIP;

    float acc[9];
#pragma unroll
    for (int s = 0; s < 9; ++s) acc[s] = 0.f;

#pragma unroll
    for (int rr = 0; rr < STRIP; ++rr) {
        int ip = ip0 + rr;               // x row (always in bounds)
        int ii = ip + sx;                // ref row (wave-uniform test)
        if ((unsigned)ii >= HH) continue;

        const float* xrow = xp + ip * WW + j0;
        const float* rrow = rp + ii * WW + j0;
        float4 xa = *(const float4*)(xrow);        // x   cols j0   .. j0+3
        float4 xb = *(const float4*)(xrow + 4);    // x   cols j0+4 .. j0+7
        float4 ra = *(const float4*)(rrow);        // ref cols j0   .. j0+3
        float4 rb = *(const float4*)(rrow + 4);    // ref cols j0+4 .. j0+7

        // halo: prev4 = ref cols j0-4..j0-1 (lane-1's rb), next4 = j0+8..j0+11
        // (shuffle version: half the ref VMEM of the R12 load version -> less
        //  L1 BW, which is now the shared resource for the 9 waves)
        float p0 = __shfl_up(rb.x, 1, 64);
        float p1 = __shfl_up(rb.y, 1, 64);
        float p2 = __shfl_up(rb.z, 1, 64);
        float p3 = __shfl_up(rb.w, 1, 64);
        if (lane == 0) { p0 = p1 = p2 = p3 = 0.f; }   // cols < 0 -> mask
        float n0 = __shfl_down(ra.x, 1, 64);
        float n1 = __shfl_down(ra.y, 1, 64);
        float n2 = __shfl_down(ra.z, 1, 64);
        float n3 = __shfl_down(ra.w, 1, 64);
        if (lane == 63) { n0 = n1 = n2 = n3 = 0.f; }  // cols >= 512 -> mask

#define P4(i) ((i) == 0 ? p0 : (i) == 1 ? p1 : (i) == 2 ? p2 : p3)
#define N4(i) ((i) == 0 ? n0 : (i) == 1 ? n1 : (i) == 2 ? n2 : n3)
#pragma unroll
        for (int syi = 0; syi < 9; ++syi) {
#pragma unroll
            for (int k = 0; k < 8; ++k) {
                int i = k + syi;         // window index 0..15 (constant)
                float wv = (i < 4)  ? P4(i)
                         : (i < 8)  ? C4(ra, i - 4)
                         : (i < 12) ? C4(rb, i - 8)
                         :            N4(i - 12);
                float xv = (k < 4) ? C4(xa, k) : C4(xb, k - 4);
                acc[syi] += xv * wv;
            }
        }
#undef P4
#undef N4
    }

    // Each wave owns 9 disjoint sims (its sx) -> no LDS combine, no atomics.
    // Wave shuffle-reduce (fp32, same math as R11), lane 0 stores fp64 partial.
    // Numerics: fp32 chunk grows 8->16 rows vs R11 (~1e-4 abs) vs inter-sim
    // gaps O(100) -> argmax stable.
    int cs = (bc % CC) * NSTRIPS + strip;            // partial slot 0..95
#pragma unroll
    for (int s = 0; s < 9; ++s) {
        float v = acc[s];
        for (int off = 32; off; off >>= 1) v += __shfl_down(v, off, 64);
        if (lane == 0)
            g_part[((size_t)b * NS + sxi * 9 + s) * SLOTS + cs] = (double)v;
    }
}

// Tiny reduce: one block per batch; thread t sums its sim's 96 consecutive
// fp64 partials (fixed order -> deterministic), then first-index argmax
// (matches jnp.argmax), writes g_best + shift tail.
__global__ __launch_bounds__(128) void k_reduce(float* __restrict__ outTail) {
    int b = blockIdx.x;
    int t = threadIdx.x;
    __shared__ double vals[NS];
    if (t < NS) {
        const double* p = g_part + ((size_t)b * NS + t) * SLOTS;
        double s = 0.0;
        for (int i = 0; i < SLOTS; ++i) s += p[i];
        vals[t] = s;
    }
    __syncthreads();
    if (t == 0) {
        int best = 0;
        double bv = vals[0];
        for (int i = 1; i < NS; ++i)
            if (vals[i] > bv) { bv = vals[i]; best = i; }   // strict >: first index wins
        g_best[b] = best;
        outTail[b * 2]     = (float)(best / 9 - 4);
        outTail[b * 2 + 1] = (float)(best % 9 - 4);
    }
}

// Pure shift-copy: reads precomputed g_best[b] (wave-uniform scalar load).
// Copy body unchanged from R11/R12 (proven exact).
__global__ __launch_bounds__(256) void k_apply(const float* __restrict__ x,
                                               float* __restrict__ out) {
    int blk = blockIdx.x;
    int bc  = blk >> 8;                 // 256 blocks per image (512 rows / 2)
    int tid = threadIdx.x;
    int b   = bc / CC;

    int bi = g_best[b];
    int sx = bi / 9 - 4;
    int sy = bi % 9 - 4;

    int row = ((blk & 255) << 1) + (tid >> 7);
    int j0  = (tid & 127) << 2;
    int is  = row - sx;
    float4 v = make_float4(0.f, 0.f, 0.f, 0.f);
    if ((unsigned)is < HH) {
        const float* src = x + (size_t)bc * IMG + is * WW;
        int js0 = j0 - sy;
        if (js0 >= 0 && js0 + 3 < WW) {
            v = *(const float4*)(src + js0);   // 4B-aligned dwordx4, exact (R2-R13)
        } else {
            float* vv = (float*)&v;
#pragma unroll
            for (int k = 0; k < 4; ++k) {
                int js = js0 + k;
                if ((unsigned)js < WW) vv[k] = src[js];
            }
        }
    }
    *(float4*)(out + (size_t)bc * IMG + row * WW + j0) = v;
}

extern "C" void kernel_launch(void* const* d_in, const int* in_sizes, int n_in,
                              void* d_out, int out_size, void* d_ws, size_t ws_size,
                              hipStream_t stream) {
    const float* xref = (const float*)d_in[0];
    const float* x    = (const float*)d_in[1];
    float* out = (float*)d_out;
    (void)d_ws; (void)ws_size;          // workspace unused (poison fill is unconditional)

    k_sims<<<NBLK, 576, 0, stream>>>(xref, x);
    k_reduce<<<BB, 128, 0, stream>>>(out + (size_t)BB * CHW);

    int applyBlocks = (BB * CC * HH) / 2;   // 3072
    k_apply<<<applyBlocks, 256, 0, stream>>>(x, out);
}